// Round 5
// baseline (520.349 us; speedup 1.0000x reference)
//
#include <hip/hip_runtime.h>
#include <cmath>

// xfb: (N=64, B=16, C=22, T=4000) fp32; WT: (B=16, M=16, C=22) fp32
// out[n,b,m] = log(diag / sum_m diag), diag = sum_t (W.x)^2 ; 1/sqrt(T) cancels.
//
// R8 post-mortem: R8 == R7 (~170 us) despite fixing request fragmentation ->
// coalescing wasn't the limit. Shared flaw: 4 waves re-read the block's
// 352-KB slab 4x with no sync; per-XCD working set (128 blocks x 352 KB
// ~ 45 MB) >> 4-MB L2, so redundancy reaches HBM (~1 GB effective fetch,
// matches R0's FETCH=774 MB signature). Floor = 360 MB / 6.3 TB/s = 57 us.
// R9: LDS-stage each 22x256 tile ONCE (float4 coalesced), barrier, all 4
// waves consume from LDS (ds_read_b128, conflict-free). Redundancy moves to
// the LDS pipe (~28 us, overlapped). Register shape keeps the proven R7/R8
// profile: wreg[4][22]=88 static + z[4]f4 + one xc f4 ~ 115 live; xc folded
// into z immediately (never 22 float4 live -- R5's spill shape avoided).
// Tail tile staged as zeros -> unguarded compute.

#define N_ 64
#define B_ 16
#define C_ 22
#define T_ 4000
#define M_ 16
#define TT_ 256          // t-columns per tile (64 float4)
#define TPAD_ 260        // LDS row stride (float), 16-B padded

__global__ __launch_bounds__(256, 1)
void OVR_CSP_kernel(const float* __restrict__ xfb,
                    const float* __restrict__ WT,
                    float* __restrict__ out) {
    const int bid  = blockIdx.x;       // n*B + b
    const int b    = bid & (B_ - 1);
    const int tid  = threadIdx.x;
    const int wave = tid >> 6;         // 0..3 -> owns m = 4*wave..4*wave+3
    const int lane = tid & 63;

    __shared__ __align__(16) float xs[C_][TPAD_];   // 22.9 KB
    __shared__ float dsh[M_];

    // This wave's 4 W rows (wave-uniform broadcast reads). 88 VGPR,
    // read-only, static-indexed.
    const float* __restrict__ wb = WT + b * (M_ * C_) + (4 * wave) * C_;
    float wreg[4][C_];
    #pragma unroll
    for (int j = 0; j < 4; ++j)
        #pragma unroll
        for (int c = 0; c < C_; ++c)
            wreg[j][c] = wb[j * C_ + c];

    const float* __restrict__ xb = xfb + (size_t)bid * (C_ * T_);

    float acc[4] = {0.f, 0.f, 0.f, 0.f};

    const int NTILE = (T_ + TT_ - 1) / TT_;   // 16 (last tile: 160 cols)
    #pragma unroll 1
    for (int tile = 0; tile < NTILE; ++tile) {
        const int t0 = tile * TT_;

        // Cooperative stage: 22 rows x 64 float4 = 1408 float4, 256 threads.
        // Fully-coalesced 1-KB wave requests; OOB columns staged as zeros.
        #pragma unroll 1
        for (int i = tid; i < C_ * (TT_ / 4); i += 256) {
            const int c  = i >> 6;
            const int f4 = i & 63;
            const int t  = t0 + 4 * f4;
            float4 v = make_float4(0.f, 0.f, 0.f, 0.f);
            if (t < T_) v = *(const float4*)(xb + c * T_ + t);
            *(float4*)&xs[c][4 * f4] = v;
        }
        __syncthreads();

        // Each wave sweeps the whole tile for its 4 m's; lane owns one
        // float4-column. xc folded into z immediately (4+16 regs live).
        float4 z[4];
        #pragma unroll
        for (int j = 0; j < 4; ++j) z[j] = make_float4(0.f, 0.f, 0.f, 0.f);

        #pragma unroll
        for (int c = 0; c < C_; ++c) {
            const float4 xc = *(const float4*)&xs[c][4 * lane];
            #pragma unroll
            for (int j = 0; j < 4; ++j) {
                z[j].x = fmaf(wreg[j][c], xc.x, z[j].x);
                z[j].y = fmaf(wreg[j][c], xc.y, z[j].y);
                z[j].z = fmaf(wreg[j][c], xc.z, z[j].z);
                z[j].w = fmaf(wreg[j][c], xc.w, z[j].w);
            }
        }
        #pragma unroll
        for (int j = 0; j < 4; ++j) {
            acc[j] = fmaf(z[j].x, z[j].x, acc[j]);
            acc[j] = fmaf(z[j].y, z[j].y, acc[j]);
            acc[j] = fmaf(z[j].z, z[j].z, acc[j]);
            acc[j] = fmaf(z[j].w, z[j].w, acc[j]);
        }
        __syncthreads();   // reads done before next tile's overwrite
    }

    // Full-wave reduction; each m owned by exactly one wave.
    #pragma unroll
    for (int j = 0; j < 4; ++j) {
        float v = acc[j];
        #pragma unroll
        for (int off = 32; off > 0; off >>= 1)
            v += __shfl_down(v, off, 64);
        if (lane == 0) dsh[4 * wave + j] = v;
    }
    __syncthreads();

    if (tid < M_) {
        float total = 0.f;
        #pragma unroll
        for (int m = 0; m < M_; ++m) total += dsh[m];
        out[(size_t)bid * M_ + tid] = logf(dsh[tid] / total);
    }
}

extern "C" void kernel_launch(void* const* d_in, const int* in_sizes, int n_in,
                              void* d_out, int out_size, void* d_ws, size_t ws_size,
                              hipStream_t stream) {
    const float* xfb = (const float*)d_in[0];
    const float* WT  = (const float*)d_in[1];
    float* out = (float*)d_out;

    dim3 grid(N_ * B_);   // 1024 blocks, one per (n,b)
    dim3 block(256);
    OVR_CSP_kernel<<<grid, block, 0, stream>>>(xfb, WT, out);
}